// Round 1
// baseline (1075.653 us; speedup 1.0000x reference)
//
#include <hip/hip_runtime.h>
#include <cstdint>

#define DMODEL 384
#define DSTATE 16
#define DCONV  4
#define DINNER 768
#define DTRANK 24
#define NPATCH 192
#define BATCHN 32
#define SEQX   193
#define MROWS  (BATCHN * NPATCH)      // 6144
#define XPN    (DTRANK + 2 * DSTATE)  // 56

// ---------------------------------------------------------------- LayerNorm
// one wave (64 threads) per (dir, b, t); gathers via scan_idx (dir-domain)
__global__ void ln_kernel(const float* __restrict__ x,
                          const float* __restrict__ fg, const float* __restrict__ fb,
                          const float* __restrict__ bg, const float* __restrict__ bb,
                          const int* __restrict__ sidx,
                          float* __restrict__ lnout) {
    int t = blockIdx.x, b = blockIdx.y, dir = blockIdx.z;
    int tid = threadIdx.x;
    int p = sidx[dir ? (NPATCH - 1 - t) : t];
    const float* src = x + ((size_t)b * SEQX + 1 + p) * DMODEL;
    float v[6];
    float s = 0.f, sq = 0.f;
#pragma unroll
    for (int i = 0; i < 6; ++i) {
        v[i] = src[tid + 64 * i];
        s += v[i];
        sq += v[i] * v[i];
    }
#pragma unroll
    for (int m = 32; m >= 1; m >>= 1) {
        s  += __shfl_xor(s, m);
        sq += __shfl_xor(sq, m);
    }
    float mean = s * (1.f / DMODEL);
    float var  = sq * (1.f / DMODEL) - mean * mean;
    float rstd = rsqrtf(var + 1e-5f);
    const float* g  = dir ? bg : fg;
    const float* be = dir ? bb : fb;
    float* dst = lnout + ((size_t)dir * MROWS + (size_t)b * NPATCH + t) * DMODEL;
#pragma unroll
    for (int i = 0; i < 6; ++i) {
        int c = tid + 64 * i;
        dst[c] = (v[i] - mean) * rstd * g[c] + be[c];
    }
}

// ---------------------------------------------------------------- GEMM
// C[m,n] = sum_k A[m,k] * W[n,k]   (W is N x K row-major, matching einsum 'ed')
// MODE 0: plain store (in_proj).           TM=8, TN=8
// MODE 1: += residual gather, store (out_proj). TN=4
// MODE 2: fusion: A split-K (fwd half from A, bwd half from A2 flipped rows),
//         bias add, scatter-store rows to d_out via scan_idx. TN=4
// MODE 3: plain with N-guard (x_proj, Nreal=56). TN=4
template <int BM, int BN, int TM, int TN, int MODE>
__global__ __launch_bounds__(256) void gemm_kernel(
    const float* __restrict__ A, const float* __restrict__ A2,
    const float* __restrict__ W, float* __restrict__ C,
    int M, int N, int K, int Nreal,
    const float* __restrict__ X, const float* __restrict__ bias,
    const int* __restrict__ sidx, int dir) {
    __shared__ float As[16][BM + 4];
    __shared__ float Ws[16][BN + 4];
    const int tid = threadIdx.x;
    const int lr = tid >> 2;          // 0..63
    const int lc = (tid & 3) << 2;    // 0,4,8,12
    const int m0 = blockIdx.y * BM;
    const int n0 = blockIdx.x * BN;
    const int NT = BN / TN;           // threads along N
    const int tx = tid % NT;
    const int ty = tid / NT;

    float acc[TM][TN];
#pragma unroll
    for (int i = 0; i < TM; ++i)
#pragma unroll
        for (int j = 0; j < TN; ++j) acc[i][j] = 0.f;

    for (int kt = 0; kt < K; kt += 16) {
        // ---- load A tile (BM x 16), transposed into LDS
#pragma unroll
        for (int r = lr; r < BM; r += 64) {
            const float* ap;
            if (MODE == 2) {
                int m  = m0 + r;
                int bb = m / NPATCH;
                int ss = m % NPATCH;
                if (kt < DMODEL)
                    ap = A + (size_t)m * DMODEL + kt + lc;
                else
                    ap = A2 + (size_t)(bb * NPATCH + (NPATCH - 1 - ss)) * DMODEL + (kt - DMODEL) + lc;
            } else {
                ap = A + (size_t)(m0 + r) * K + kt + lc;
            }
            float4 v = *(const float4*)ap;
            As[lc + 0][r] = v.x;
            As[lc + 1][r] = v.y;
            As[lc + 2][r] = v.z;
            As[lc + 3][r] = v.w;
        }
        // ---- load W tile (BN x 16), transposed into LDS
#pragma unroll
        for (int r = lr; r < BN; r += 64) {
            float4 v = make_float4(0.f, 0.f, 0.f, 0.f);
            if (MODE != 3 || (n0 + r) < Nreal)
                v = *(const float4*)(W + (size_t)(n0 + r) * K + kt + lc);
            Ws[lc + 0][r] = v.x;
            Ws[lc + 1][r] = v.y;
            Ws[lc + 2][r] = v.z;
            Ws[lc + 3][r] = v.w;
        }
        __syncthreads();
#pragma unroll
        for (int kk = 0; kk < 16; ++kk) {
            float a[TM], w[TN];
#pragma unroll
            for (int i = 0; i < TM; ++i) a[i] = As[kk][ty * TM + i];
#pragma unroll
            for (int j = 0; j < TN; ++j) w[j] = Ws[kk][tx * TN + j];
#pragma unroll
            for (int i = 0; i < TM; ++i)
#pragma unroll
                for (int j = 0; j < TN; ++j) acc[i][j] = fmaf(a[i], w[j], acc[i][j]);
        }
        __syncthreads();
    }

    // ---- epilogue
#pragma unroll
    for (int i = 0; i < TM; ++i) {
        int m = m0 + ty * TM + i;
        if (MODE == 0) {
#pragma unroll
            for (int j = 0; j < TN; j += 4) {
                float4 v = make_float4(acc[i][j], acc[i][j + 1], acc[i][j + 2], acc[i][j + 3]);
                *(float4*)(C + (size_t)m * N + n0 + tx * TN + j) = v;
            }
        } else if (MODE == 3) {
            int col = n0 + tx * TN;
            if (col < Nreal) {
                float4 v = make_float4(acc[i][0], acc[i][1], acc[i][2], acc[i][3]);
                *(float4*)(C + (size_t)m * Nreal + col) = v;
            }
        } else if (MODE == 1) {
            int bb = m / NPATCH, t = m % NPATCH;
            int p = sidx[dir ? (NPATCH - 1 - t) : t];
            int col = n0 + tx * TN;
            float4 r4 = *(const float4*)(X + ((size_t)bb * SEQX + 1 + p) * DMODEL + col);
            float4 v = make_float4(acc[i][0] + r4.x, acc[i][1] + r4.y,
                                   acc[i][2] + r4.z, acc[i][3] + r4.w);
            *(float4*)(C + (size_t)m * N + col) = v;
        } else { // MODE 2
            int bb = m / NPATCH, ss = m % NPATCH;
            int p = sidx[ss];
            int col = n0 + tx * TN;
            float4 bv = *(const float4*)(bias + col);
            float4 v = make_float4(acc[i][0] + bv.x, acc[i][1] + bv.y,
                                   acc[i][2] + bv.z, acc[i][3] + bv.w);
            *(float4*)(C + ((size_t)bb * SEQX + 1 + p) * DMODEL + col) = v;
        }
    }
}

// ---------------------------------------------------------------- conv1d(k=4, causal) + SiLU
__global__ void conv_silu_kernel(const float* __restrict__ xz,
                                 const float* __restrict__ fw, const float* __restrict__ fb,
                                 const float* __restrict__ bw, const float* __restrict__ bb2,
                                 float* __restrict__ xc) {
    size_t idx = (size_t)blockIdx.x * 256 + threadIdx.x; // < 2*6144*768
    int d = (int)(idx % DINNER);
    size_t row = idx / DINNER;          // dir*6144 + b*192 + t
    int t = (int)(row % NPATCH);
    int dir = (int)(row / MROWS);
    const float* w = (dir ? bw : fw) + d * DCONV;
    float acc = (dir ? bb2 : fb)[d];
    const float* base = xz + (row - t) * (2 * DINNER) + d;
#pragma unroll
    for (int k = 0; k < 4; ++k) {
        int tt = t - 3 + k;
        if (tt >= 0) acc = fmaf(base[(size_t)tt * (2 * DINNER)], w[k], acc);
    }
    xc[idx] = acc / (1.f + __expf(-acc)); // silu
}

// ---------------------------------------------------------------- selective scan (+dt proj, +u*D, +z gate)
__global__ __launch_bounds__(256) void scan_kernel(
    const float* __restrict__ xc, const float* __restrict__ xz,
    const float* __restrict__ xdbl,
    const float* __restrict__ f_dtw, const float* __restrict__ f_dtb,
    const float* __restrict__ f_Alog, const float* __restrict__ f_D,
    const float* __restrict__ b_dtw, const float* __restrict__ b_dtb,
    const float* __restrict__ b_Alog, const float* __restrict__ b_D,
    float* __restrict__ yg) {
    int chunk = blockIdx.x; // 0..2
    int b = blockIdx.y;
    int dir = blockIdx.z;
    int tid = threadIdx.x;
    int d = chunk * 256 + tid;

    const float* dtw_p = (dir ? b_dtw : f_dtw) + (size_t)d * DTRANK;
    float dtw[DTRANK];
#pragma unroll
    for (int r = 0; r < DTRANK; ++r) dtw[r] = dtw_p[r];
    const float* al = (dir ? b_Alog : f_Alog) + (size_t)d * DSTATE;
    float Areg[DSTATE];
#pragma unroll
    for (int n = 0; n < DSTATE; ++n) Areg[n] = -__expf(al[n]);
    float dtb = (dir ? b_dtb : f_dtb)[d];
    float Dp  = (dir ? b_D : f_D)[d];
    float h[DSTATE];
#pragma unroll
    for (int n = 0; n < DSTATE; ++n) h[n] = 0.f;

    size_t rowbase = (size_t)dir * MROWS + (size_t)b * NPATCH; // row of t=0
    const float* xc_p  = xc + rowbase * DINNER + d;
    const float* z_p   = xz + rowbase * (2 * DINNER) + DINNER + d;
    float* y_p         = yg + rowbase * DINNER + d;
    const float* dbl_p = xdbl + rowbase * XPN;

    __shared__ float sdbl[8][XPN];
    for (int t0 = 0; t0 < NPATCH; t0 += 8) {
        __syncthreads();
        for (int i = tid; i < 8 * XPN; i += 256) {
            sdbl[i / XPN][i % XPN] = dbl_p[(size_t)(t0 + i / XPN) * XPN + (i % XPN)];
        }
        __syncthreads();
#pragma unroll 1
        for (int tt = 0; tt < 8; ++tt) {
            int t = t0 + tt;
            float u  = xc_p[(size_t)t * DINNER];
            float zz = z_p[(size_t)t * (2 * DINNER)];
            float dtr = dtb;
#pragma unroll
            for (int r = 0; r < DTRANK; ++r) dtr = fmaf(sdbl[tt][r], dtw[r], dtr);
            // softplus (stable)
            float dt = fmaxf(dtr, 0.f) + log1pf(__expf(-fabsf(dtr)));
            float dtu = dt * u;
            float y = 0.f;
#pragma unroll
            for (int n = 0; n < DSTATE; ++n) {
                float dA = __expf(dt * Areg[n]);
                h[n] = fmaf(dA, h[n], dtu * sdbl[tt][DTRANK + n]);
                y = fmaf(h[n], sdbl[tt][DTRANK + DSTATE + n], y);
            }
            y = fmaf(u, Dp, y);
            float gate = zz / (1.f + __expf(-zz));
            y_p[(size_t)t * DINNER] = y * gate;
        }
    }
}

// ---------------------------------------------------------------- cls passthrough
__global__ void cls_kernel(const float* __restrict__ x, float* __restrict__ out) {
    int b = blockIdx.x;
    int tid = threadIdx.x;
    out[(size_t)b * SEQX * DMODEL + tid] = x[(size_t)b * SEQX * DMODEL + tid];
}

// ---------------------------------------------------------------- launch
extern "C" void kernel_launch(void* const* d_in, const int* in_sizes, int n_in,
                              void* d_out, int out_size, void* d_ws, size_t ws_size,
                              hipStream_t stream) {
    const float* x       = (const float*)d_in[0];
    const float* f_ln_g  = (const float*)d_in[1];
    const float* f_ln_b  = (const float*)d_in[2];
    const float* f_in_w  = (const float*)d_in[3];
    const float* f_convw = (const float*)d_in[4];
    const float* f_convb = (const float*)d_in[5];
    const float* f_x_w   = (const float*)d_in[6];
    const float* f_dt_w  = (const float*)d_in[7];
    const float* f_dt_b  = (const float*)d_in[8];
    const float* f_A_log = (const float*)d_in[9];
    const float* f_D     = (const float*)d_in[10];
    const float* f_out_w = (const float*)d_in[11];
    const float* b_ln_g  = (const float*)d_in[12];
    const float* b_ln_b  = (const float*)d_in[13];
    const float* b_in_w  = (const float*)d_in[14];
    const float* b_convw = (const float*)d_in[15];
    const float* b_convb = (const float*)d_in[16];
    const float* b_x_w   = (const float*)d_in[17];
    const float* b_dt_w  = (const float*)d_in[18];
    const float* b_dt_b  = (const float*)d_in[19];
    const float* b_A_log = (const float*)d_in[20];
    const float* b_D     = (const float*)d_in[21];
    const float* b_out_w = (const float*)d_in[22];
    const float* fusionw = (const float*)d_in[23];
    const float* fusionb = (const float*)d_in[24];
    const int*   sidx    = (const int*)d_in[25];

    float* ws = (float*)d_ws;
    float* ln   = ws;                         // 2*6144*384  = 4,718,592 f
    float* xz   = ln + (size_t)2 * MROWS * DMODEL;      // 2*6144*1536 = 18,874,368 f
    float* xc   = xz + (size_t)2 * MROWS * 2 * DINNER;  // 2*6144*768  = 9,437,184 f
    float* xdbl = xc + (size_t)2 * MROWS * DINNER;      // 2*6144*56   = 688,128 f
    float* yg   = xc;   // scan reads xc[t,d] before writing yg[t,d] — safe in-place
    float* blk  = ln;   // ln dead after in_proj; reuse for block outputs
    float* outp = (float*)d_out;

    // 1. LayerNorm (both dirs, dir-domain ordering)
    ln_kernel<<<dim3(NPATCH, BATCHN, 2), 64, 0, stream>>>(
        x, f_ln_g, f_ln_b, b_ln_g, b_ln_b, sidx, ln);

    // 2. in_proj: M=6144, N=1536, K=384 per dir
    for (int dir = 0; dir < 2; ++dir) {
        gemm_kernel<128, 128, 8, 8, 0><<<dim3(1536 / 128, MROWS / 128), 256, 0, stream>>>(
            ln + (size_t)dir * MROWS * DMODEL, nullptr,
            dir ? b_in_w : f_in_w,
            xz + (size_t)dir * MROWS * 2 * DINNER,
            MROWS, 2 * DINNER, DMODEL, 2 * DINNER, nullptr, nullptr, nullptr, dir);
    }

    // 3. causal conv + SiLU
    conv_silu_kernel<<<(2 * MROWS * DINNER) / 256, 256, 0, stream>>>(
        xz, f_convw, f_convb, b_convw, b_convb, xc);

    // 4. x_proj: M=6144, N=56 (tile 64), K=768 per dir
    for (int dir = 0; dir < 2; ++dir) {
        gemm_kernel<128, 64, 8, 4, 3><<<dim3(1, MROWS / 128), 256, 0, stream>>>(
            xc + (size_t)dir * MROWS * DINNER, nullptr,
            dir ? b_x_w : f_x_w,
            xdbl + (size_t)dir * MROWS * XPN,
            MROWS, 64, DINNER, XPN, nullptr, nullptr, nullptr, dir);
    }

    // 5. selective scan + dt-proj + u*D + z-gate (in-place over xc)
    scan_kernel<<<dim3(DINNER / 256, BATCHN, 2), 256, 0, stream>>>(
        xc, xz, xdbl,
        f_dt_w, f_dt_b, f_A_log, f_D,
        b_dt_w, b_dt_b, b_A_log, b_D, yg);

    // 6. out_proj: M=6144, N=384, K=768 per dir, + residual gather
    for (int dir = 0; dir < 2; ++dir) {
        gemm_kernel<128, 64, 8, 4, 1><<<dim3(DMODEL / 64, MROWS / 128), 256, 0, stream>>>(
            yg + (size_t)dir * MROWS * DINNER, nullptr,
            dir ? b_out_w : f_out_w,
            blk + (size_t)dir * MROWS * DMODEL,
            MROWS, DMODEL, DINNER, DMODEL, x, nullptr, sidx, dir);
    }

    // 7. fusion: M=6144, N=384, K=768 (split: fwd half + flipped bwd half),
    //    bias + scatter into d_out
    gemm_kernel<128, 64, 8, 4, 2><<<dim3(DMODEL / 64, MROWS / 128), 256, 0, stream>>>(
        blk, blk + (size_t)MROWS * DMODEL,
        fusionw, outp,
        MROWS, DMODEL, 2 * DMODEL, DMODEL, nullptr, fusionb, sidx, 0);

    // 8. cls passthrough
    cls_kernel<<<BATCHN, DMODEL, 0, stream>>>(x, outp);
}

// Round 2
// 401.752 us; speedup vs baseline: 2.6774x; 2.6774x over previous
//
#include <hip/hip_runtime.h>
#include <cstdint>

#define DMODEL 384
#define DSTATE 16
#define DCONV  4
#define DINNER 768
#define DTRANK 24
#define NPATCH 192
#define BATCHN 32
#define SEQX   193
#define MROWS  (BATCHN * NPATCH)      // 6144
#define XPN    (DTRANK + 2 * DSTATE)  // 56

typedef unsigned short ushort8 __attribute__((ext_vector_type(8)));
typedef __bf16 bf16x8 __attribute__((ext_vector_type(8)));
typedef float f32x4 __attribute__((ext_vector_type(4)));

static __device__ inline unsigned short f2bf(float f) {
    unsigned int u = __float_as_uint(f);
    u = (u + 0x7fffu + ((u >> 16) & 1u)) >> 16;
    return (unsigned short)u;
}
static __device__ inline bf16x8 as_bf(ushort8 u) {
    union { ushort8 u; bf16x8 b; } c; c.u = u; return c.b;
}

// ---------------------------------------------------------------- LayerNorm -> bf16
__global__ void ln_kernel(const float* __restrict__ x,
                          const float* __restrict__ fg, const float* __restrict__ fb,
                          const float* __restrict__ bg, const float* __restrict__ bb,
                          const int* __restrict__ sidx,
                          unsigned short* __restrict__ lnb) {
    int t = blockIdx.x, b = blockIdx.y, dir = blockIdx.z;
    int tid = threadIdx.x;
    int p = sidx[dir ? (NPATCH - 1 - t) : t];
    const float* src = x + ((size_t)b * SEQX + 1 + p) * DMODEL;
    float v[6];
    float s = 0.f, sq = 0.f;
#pragma unroll
    for (int i = 0; i < 6; ++i) {
        v[i] = src[tid + 64 * i];
        s += v[i];
        sq += v[i] * v[i];
    }
#pragma unroll
    for (int m = 32; m >= 1; m >>= 1) {
        s  += __shfl_xor(s, m);
        sq += __shfl_xor(sq, m);
    }
    float mean = s * (1.f / DMODEL);
    float var  = sq * (1.f / DMODEL) - mean * mean;
    float rstd = rsqrtf(var + 1e-5f);
    const float* g  = dir ? bg : fg;
    const float* be = dir ? bb : fb;
    unsigned short* dst = lnb + ((size_t)dir * MROWS + (size_t)b * NPATCH + t) * DMODEL;
#pragma unroll
    for (int i = 0; i < 6; ++i) {
        int c = tid + 64 * i;
        dst[c] = f2bf((v[i] - mean) * rstd * g[c] + be[c]);
    }
}

// ---------------------------------------------------------------- weight fp32->bf16
__global__ void wconv_kernel(const float* __restrict__ w0, const float* __restrict__ w1,
                             const float* __restrict__ w2, const float* __restrict__ w3,
                             const float* __restrict__ w4, const float* __restrict__ w5,
                             const float* __restrict__ w6,
                             unsigned short* __restrict__ wb) {
    int i = blockIdx.x * 256 + threadIdx.x;
    const int S0 = 1536 * 384, S1 = 56 * 768, S2 = 384 * 768;
    float v;
    if      (i < S0)                     v = w0[i];
    else if (i < 2*S0)                   v = w1[i - S0];
    else if (i < 2*S0 + S1)              v = w2[i - 2*S0];
    else if (i < 2*S0 + 2*S1)            v = w3[i - 2*S0 - S1];
    else if (i < 2*S0 + 2*S1 + S2)       v = w4[i - 2*S0 - 2*S1];
    else if (i < 2*S0 + 2*S1 + 2*S2)     v = w5[i - 2*S0 - 2*S1 - S2];
    else if (i < 2*S0 + 2*S1 + 3*S2)     v = w6[i - 2*S0 - 2*S1 - 2*S2];
    else return;
    wb[i] = f2bf(v);
}

// ---------------------------------------------------------------- bf16 MFMA GEMM
// C[m,n] = sum_k A[m,k] * W[n,k], A,W bf16, acc fp32.
// 128x128 tile, 4 waves in 2x2, each wave 4x4 of 16x16x32 MFMA.
// MODE 0: in_proj  -> fp32 C [M][N]
// MODE 1: x_proj   -> fp32 C [M][56], guard col<56, W rows guarded by Nreal
// MODE 2: out_proj -> bf16 C [M][384] = acc + residual-gather(X)
// MODE 3: fusion   -> fp32 scatter to out: acc + bias, A split (fwd | flipped bwd)
template <int MODE>
__global__ __launch_bounds__(256) void mfma_gemm(
    const unsigned short* __restrict__ A, const unsigned short* __restrict__ A2,
    const unsigned short* __restrict__ Wf, const unsigned short* __restrict__ Wb,
    float* __restrict__ Cf, unsigned short* __restrict__ Cb,
    int N, int K, int Nreal, int Ka,
    const float* __restrict__ X, const float* __restrict__ bias,
    const int* __restrict__ sidx) {
    __shared__ unsigned short As[128][72];
    __shared__ unsigned short Bs[128][72];
    const int tid = threadIdx.x;
    const int m0 = blockIdx.y * 128;
    const int n0 = blockIdx.x * 128;
    const unsigned short* W = (MODE == 3) ? Wf : ((m0 >= MROWS) ? Wb : Wf);

    f32x4 acc[4][4];
#pragma unroll
    for (int i = 0; i < 4; ++i)
#pragma unroll
        for (int j = 0; j < 4; ++j) acc[i][j] = (f32x4){0.f, 0.f, 0.f, 0.f};

    const int lr = tid >> 3;          // 0..31
    const int kc = (tid & 7) * 8;     // 0..56
    const int lane = tid & 63;
    const int wv = tid >> 6;
    const int mb = (wv >> 1) * 64, nb = (wv & 1) * 64;
    const int qr = lane >> 4, c16 = lane & 15;

    for (int kt = 0; kt < K; kt += 64) {
#pragma unroll
        for (int p = 0; p < 4; ++p) {
            int r = lr + p * 32;
            const unsigned short* ap;
            if (MODE == 3) {
                int gr = m0 + r;
                if (kt < DMODEL) {
                    ap = A + (size_t)gr * DMODEL + kt + kc;
                } else {
                    int b = gr / NPATCH, ss = gr % NPATCH;
                    ap = A2 + (size_t)(b * NPATCH + NPATCH - 1 - ss) * DMODEL + (kt - DMODEL) + kc;
                }
            } else {
                ap = A + (size_t)(m0 + r) * Ka + kt + kc;
            }
            *(ushort8*)&As[r][kc] = *(const ushort8*)ap;
            int nr = n0 + r;
            ushort8 wvv = {0, 0, 0, 0, 0, 0, 0, 0};
            if (nr < Nreal) wvv = *(const ushort8*)(W + (size_t)nr * K + kt + kc);
            *(ushort8*)&Bs[r][kc] = wvv;
        }
        __syncthreads();
#pragma unroll
        for (int ks = 0; ks < 64; ks += 32) {
            bf16x8 af[4], bfr[4];
#pragma unroll
            for (int i = 0; i < 4; ++i)
                af[i] = as_bf(*(const ushort8*)&As[mb + i * 16 + c16][ks + qr * 8]);
#pragma unroll
            for (int j = 0; j < 4; ++j)
                bfr[j] = as_bf(*(const ushort8*)&Bs[nb + j * 16 + c16][ks + qr * 8]);
#pragma unroll
            for (int i = 0; i < 4; ++i)
#pragma unroll
                for (int j = 0; j < 4; ++j)
                    acc[i][j] = __builtin_amdgcn_mfma_f32_16x16x32_bf16(af[i], bfr[j], acc[i][j], 0, 0, 0);
        }
        __syncthreads();
    }

#pragma unroll
    for (int i = 0; i < 4; ++i) {
#pragma unroll
        for (int r = 0; r < 4; ++r) {
            int row = m0 + mb + i * 16 + qr * 4 + r;
            // precompute row-dependent epilogue data
            int pidx = 0; const float* xres = nullptr; size_t obase = 0;
            if (MODE == 2) {
                int dirM = row >= MROWS;
                int rem = row - dirM * MROWS;
                int b = rem / NPATCH, t = rem % NPATCH;
                pidx = sidx[dirM ? (NPATCH - 1 - t) : t];
                xres = X + ((size_t)b * SEQX + 1 + pidx) * DMODEL;
            } else if (MODE == 3) {
                int b = row / NPATCH, ss = row % NPATCH;
                pidx = sidx[ss];
                obase = ((size_t)b * SEQX + 1 + pidx) * DMODEL;
            }
#pragma unroll
            for (int j = 0; j < 4; ++j) {
                int col = n0 + nb + j * 16 + c16;
                float v = acc[i][j][r];
                if (MODE == 0) {
                    Cf[(size_t)row * N + col] = v;
                } else if (MODE == 1) {
                    if (col < XPN) Cf[(size_t)row * XPN + col] = v;
                } else if (MODE == 2) {
                    Cb[(size_t)row * DMODEL + col] = f2bf(v + xres[col]);
                } else {
                    Cf[obase + col] = v + bias[col];
                }
            }
        }
    }
}

// ---------------------------------------------------------------- conv1d(k=4, causal) + SiLU
__global__ void conv_silu_kernel(const float* __restrict__ xz,
                                 const float* __restrict__ fw, const float* __restrict__ fb,
                                 const float* __restrict__ bw, const float* __restrict__ bb2,
                                 float* __restrict__ xc, unsigned short* __restrict__ xcb) {
    size_t idx = (size_t)blockIdx.x * 256 + threadIdx.x; // < 2*6144*768
    int d = (int)(idx % DINNER);
    size_t row = idx / DINNER;          // dir*6144 + b*192 + t
    int t = (int)(row % NPATCH);
    int dir = (int)(row / MROWS);
    const float* w = (dir ? bw : fw) + d * DCONV;
    float acc = (dir ? bb2 : fb)[d];
    const float* base = xz + (row - t) * (2 * DINNER) + d;
#pragma unroll
    for (int k = 0; k < 4; ++k) {
        int tt = t - 3 + k;
        if (tt >= 0) acc = fmaf(base[(size_t)tt * (2 * DINNER)], w[k], acc);
    }
    float s = acc / (1.f + __expf(-acc));
    xc[idx] = s;
    xcb[idx] = f2bf(s);
}

// ---------------------------------------------------------------- dt projection + softplus
// dt[row][d] = softplus(sum_r xdbl[row][r]*dt_w[d][r] + dt_b[d]) stored into xz xm-half
__global__ __launch_bounds__(256) void dtproj_kernel(
    const float* __restrict__ xdbl,
    const float* __restrict__ f_dtw, const float* __restrict__ f_dtb,
    const float* __restrict__ b_dtw, const float* __restrict__ b_dtb,
    float* __restrict__ xz) {
    int d = blockIdx.x * 256 + threadIdx.x;      // 0..767
    size_t row0 = (size_t)blockIdx.y * 8;        // 8 rows per block
    int dir = (row0 >= MROWS);
    __shared__ float sr[8][DTRANK];
    for (int i = threadIdx.x; i < 8 * DTRANK; i += 256)
        sr[i / DTRANK][i % DTRANK] = xdbl[(row0 + i / DTRANK) * XPN + (i % DTRANK)];
    const float* wp = (dir ? b_dtw : f_dtw) + (size_t)d * DTRANK;
    float wreg[DTRANK];
#pragma unroll
    for (int r = 0; r < DTRANK; ++r) wreg[r] = wp[r];
    float bv = (dir ? b_dtb : f_dtb)[d];
    __syncthreads();
#pragma unroll
    for (int rr = 0; rr < 8; ++rr) {
        float acc = bv;
#pragma unroll
        for (int r = 0; r < DTRANK; ++r) acc = fmaf(sr[rr][r], wreg[r], acc);
        float dt = fmaxf(acc, 0.f) + log1pf(__expf(-fabsf(acc)));
        xz[(row0 + rr) * (2 * DINNER) + d] = dt;
    }
}

// ---------------------------------------------------------------- selective scan
// 4 threads per channel (4 states each); dt precomputed; y shuffle-reduced;
// output gated with z, written bf16.
__global__ __launch_bounds__(256) void scan_kernel(
    const float* __restrict__ xc, const float* __restrict__ xz,
    const float* __restrict__ xdbl,
    const float* __restrict__ f_Alog, const float* __restrict__ f_D,
    const float* __restrict__ b_Alog, const float* __restrict__ b_D,
    unsigned short* __restrict__ ygb) {
    const int tid = threadIdx.x;
    const int dl = tid >> 2;          // 0..63 channel within block
    const int ng = tid & 3;           // state group
    const int d0 = blockIdx.x * 64;
    const int b  = blockIdx.y;
    const int dir = blockIdx.z;
    const int d = d0 + dl;
    const size_t rb = (size_t)dir * MROWS + (size_t)b * NPATCH;

    const float* al = (dir ? b_Alog : f_Alog) + (size_t)d * DSTATE + ng * 4;
    float Ar[4];
#pragma unroll
    for (int j = 0; j < 4; ++j) Ar[j] = -__expf(al[j]);
    float Dp = (dir ? b_D : f_D)[d];
    float h[4] = {0.f, 0.f, 0.f, 0.f};

    __shared__ float s_u[16][64];
    __shared__ float s_dt[16][64];
    __shared__ float s_z[16][64];
    __shared__ float s_bc[16][32];

    for (int t0 = 0; t0 < NPATCH; t0 += 16) {
        __syncthreads();
        for (int i = tid; i < 16 * 64; i += 256) {
            int ts = i >> 6, dd = i & 63;
            size_t rw = rb + t0 + ts;
            s_u[ts][dd]  = xc[rw * DINNER + d0 + dd];
            s_dt[ts][dd] = xz[rw * (2 * DINNER) + d0 + dd];
            s_z[ts][dd]  = xz[rw * (2 * DINNER) + DINNER + d0 + dd];
        }
        for (int i = tid; i < 16 * 32; i += 256) {
            int ts = i >> 5, nn = i & 31;
            s_bc[ts][nn] = xdbl[(rb + t0 + ts) * XPN + DTRANK + nn];
        }
        __syncthreads();
#pragma unroll 1
        for (int tt = 0; tt < 16; ++tt) {
            float dtv = s_dt[tt][dl];
            float u   = s_u[tt][dl];
            float dtu = dtv * u;
            float y = 0.f;
#pragma unroll
            for (int j = 0; j < 4; ++j) {
                float dA = __expf(dtv * Ar[j]);
                h[j] = fmaf(dA, h[j], dtu * s_bc[tt][ng * 4 + j]);
                y = fmaf(h[j], s_bc[tt][16 + ng * 4 + j], y);
            }
            y += __shfl_xor(y, 1);
            y += __shfl_xor(y, 2);
            if (ng == 0) {
                float z = s_z[tt][dl];
                float yo = fmaf(u, Dp, y);
                float g = z / (1.f + __expf(-z));
                ygb[(rb + t0 + tt) * DINNER + d] = f2bf(yo * g);
            }
        }
    }
}

// ---------------------------------------------------------------- cls passthrough
__global__ void cls_kernel(const float* __restrict__ x, float* __restrict__ out) {
    int b = blockIdx.x;
    int tid = threadIdx.x;
    out[(size_t)b * SEQX * DMODEL + tid] = x[(size_t)b * SEQX * DMODEL + tid];
}

// ---------------------------------------------------------------- launch
extern "C" void kernel_launch(void* const* d_in, const int* in_sizes, int n_in,
                              void* d_out, int out_size, void* d_ws, size_t ws_size,
                              hipStream_t stream) {
    const float* x       = (const float*)d_in[0];
    const float* f_ln_g  = (const float*)d_in[1];
    const float* f_ln_b  = (const float*)d_in[2];
    const float* f_in_w  = (const float*)d_in[3];
    const float* f_convw = (const float*)d_in[4];
    const float* f_convb = (const float*)d_in[5];
    const float* f_x_w   = (const float*)d_in[6];
    const float* f_dt_w  = (const float*)d_in[7];
    const float* f_dt_b  = (const float*)d_in[8];
    const float* f_A_log = (const float*)d_in[9];
    const float* f_D     = (const float*)d_in[10];
    const float* f_out_w = (const float*)d_in[11];
    const float* b_ln_g  = (const float*)d_in[12];
    const float* b_ln_b  = (const float*)d_in[13];
    const float* b_in_w  = (const float*)d_in[14];
    const float* b_convw = (const float*)d_in[15];
    const float* b_convb = (const float*)d_in[16];
    const float* b_x_w   = (const float*)d_in[17];
    const float* b_dt_w  = (const float*)d_in[18];
    const float* b_dt_b  = (const float*)d_in[19];
    const float* b_A_log = (const float*)d_in[20];
    const float* b_D     = (const float*)d_in[21];
    const float* b_out_w = (const float*)d_in[22];
    const float* fusionw = (const float*)d_in[23];
    const float* fusionb = (const float*)d_in[24];
    const int*   sidx    = (const int*)d_in[25];

    float* ws = (float*)d_ws;
    float* xz   = ws;                                    // 2*6144*1536 f
    float* xc   = xz + (size_t)2 * MROWS * 2 * DINNER;   // 2*6144*768  f
    float* xdbl = xc + (size_t)2 * MROWS * DINNER;       // 2*6144*56   f
    unsigned short* lnb = (unsigned short*)(xdbl + (size_t)2 * MROWS * XPN); // 2*6144*384 u16
    unsigned short* xcb = lnb + (size_t)2 * MROWS * DMODEL;                  // 2*6144*768 u16
    unsigned short* wb  = xcb + (size_t)2 * MROWS * DINNER;                  // 2150400 u16
    unsigned short* blkb = lnb;   // reuse (lnb dead after in_proj)
    unsigned short* ygb  = xcb;   // reuse (xcb dead after x_proj)
    float* outp = (float*)d_out;

    const int S0 = 1536 * 384, S1 = 56 * 768, S2 = 384 * 768;
    const unsigned short* winF = wb;
    const unsigned short* winB = wb + S0;
    const unsigned short* wxF  = wb + 2 * S0;
    const unsigned short* wxB  = wb + 2 * S0 + S1;
    const unsigned short* woF  = wb + 2 * S0 + 2 * S1;
    const unsigned short* woB  = wb + 2 * S0 + 2 * S1 + S2;
    const unsigned short* wfus = wb + 2 * S0 + 2 * S1 + 2 * S2;
    const int WTOT = 2 * S0 + 2 * S1 + 3 * S2;

    // 0. weights -> bf16
    wconv_kernel<<<(WTOT + 255) / 256, 256, 0, stream>>>(
        f_in_w, b_in_w, f_x_w, b_x_w, f_out_w, b_out_w, fusionw, wb);

    // 1. LayerNorm -> bf16 (both dirs, dir-domain ordering)
    ln_kernel<<<dim3(NPATCH, BATCHN, 2), 64, 0, stream>>>(
        x, f_ln_g, f_ln_b, b_ln_g, b_ln_b, sidx, lnb);

    // 2. in_proj: M=12288, N=1536, K=384 -> xz fp32
    mfma_gemm<0><<<dim3(1536 / 128, (2 * MROWS) / 128), 256, 0, stream>>>(
        lnb, nullptr, winF, winB, xz, nullptr,
        2 * DINNER, DMODEL, 2 * DINNER, DMODEL, nullptr, nullptr, nullptr);

    // 3. causal conv + SiLU -> xc fp32 + xcb bf16
    conv_silu_kernel<<<(2 * MROWS * DINNER) / 256, 256, 0, stream>>>(
        xz, f_convw, f_convb, b_convw, b_convb, xc, xcb);

    // 4. x_proj: M=12288, N=56 (tile 128), K=768 -> xdbl fp32
    mfma_gemm<1><<<dim3(1, (2 * MROWS) / 128), 256, 0, stream>>>(
        xcb, nullptr, wxF, wxB, xdbl, nullptr,
        128, DINNER, XPN, DINNER, nullptr, nullptr, nullptr);

    // 5. dt projection + softplus -> xz xm-half (dead after conv)
    dtproj_kernel<<<dim3(DINNER / 256, (2 * MROWS) / 8), 256, 0, stream>>>(
        xdbl, f_dt_w, f_dt_b, b_dt_w, b_dt_b, xz);

    // 6. selective scan + u*D + z-gate -> ygb bf16
    scan_kernel<<<dim3(DINNER / 64, BATCHN, 2), 256, 0, stream>>>(
        xc, xz, xdbl, f_A_log, f_D, b_A_log, b_D, ygb);

    // 7. out_proj: M=12288, N=384, K=768, + residual gather -> blkb bf16
    mfma_gemm<2><<<dim3(DMODEL / 128, (2 * MROWS) / 128), 256, 0, stream>>>(
        ygb, nullptr, woF, woB, nullptr, blkb,
        DMODEL, DINNER, DMODEL, DINNER, x, nullptr, sidx);

    // 8. fusion: M=6144, N=384, K=768 (fwd half | flipped bwd half), +bias, scatter
    mfma_gemm<3><<<dim3(DMODEL / 128, MROWS / 128), 256, 0, stream>>>(
        blkb, blkb + (size_t)MROWS * DMODEL, wfus, nullptr, outp, nullptr,
        DMODEL, 2 * DMODEL, DMODEL, DMODEL, nullptr, fusionb, sidx);

    // 9. cls passthrough
    cls_kernel<<<BATCHN, DMODEL, 0, stream>>>(x, outp);
}